// Round 7
// baseline (343.562 us; speedup 1.0000x reference)
//
#include <hip/hip_runtime.h>
#include <stdint.h>

#define B_ 4
#define L_ 2048
#define H_ 8
#define E_ 64
#define S_ 2048

typedef __bf16 bf16x8 __attribute__((ext_vector_type(8)));
typedef _Float16 f16x8 __attribute__((ext_vector_type(8)));
typedef _Float16 f16x4 __attribute__((ext_vector_type(4)));
typedef float f32x4 __attribute__((ext_vector_type(4)));
typedef unsigned short u16;
typedef u16 u16x4 __attribute__((ext_vector_type(4)));

__device__ __forceinline__ u16 f32_to_bf16(float f) {
  union { float f; uint32_t u; } x;
  x.f = f;
  uint32_t u = x.u;
  return (u16)((u + 0x7FFFu + ((u >> 16) & 1u)) >> 16);
}

// q' = bf16(q * tau[b]/sqrt(E) * log2e), k' = bf16(k), delta' = delta/sqrt(E)*log2e
__global__ __launch_bounds__(256) void prep_qkd(
    const float* __restrict__ q, const float* __restrict__ k,
    const float* __restrict__ tau, const float* __restrict__ delta,
    u16* __restrict__ qb, u16* __restrict__ kb, float* __restrict__ dl) {
  int idx = blockIdx.x * 256 + threadIdx.x;  // 0 .. 1048575
  int i4 = idx * 4;
  int b = i4 >> 20;
  const float C = 0.125f * 1.44269504088896f;
  float ts = tau[b] * C;
  f32x4 qv = *(const f32x4*)(q + i4);
  f32x4 kv = *(const f32x4*)(k + i4);
  u16x4 qs, ks;
#pragma unroll
  for (int j = 0; j < 4; ++j) {
    qs[j] = f32_to_bf16(qv[j] * ts);
    ks[j] = f32_to_bf16(kv[j]);
  }
  *(u16x4*)(qb + i4) = qs;
  *(u16x4*)(kb + i4) = ks;
  if (idx < (B_ * S_) / 4) {
    f32x4 dv = *(const f32x4*)(delta + i4);
    f32x4 ds = {dv[0] * C, dv[1] * C, dv[2] * C, dv[3] * C};
    *(f32x4*)(dl + i4) = ds;
  }
}

// V [B,S,H,E] f32 -> V' [B,H,E,S] fp16 (tiled transpose)
__global__ __launch_bounds__(256) void prep_v(const float* __restrict__ v,
                                              u16* __restrict__ vb) {
  __shared__ float t[32][33];
  int bid = blockIdx.x;
  int et = bid & 1;
  int st = (bid >> 1) & 63;
  int h = (bid >> 7) & 7;
  int b = bid >> 10;
  int tx = threadIdx.x & 31;
  int ty = threadIdx.x >> 5;
#pragma unroll
  for (int k2 = 0; k2 < 4; ++k2) {
    int s = st * 32 + ty + 8 * k2;
    int e = et * 32 + tx;
    t[ty + 8 * k2][tx] = v[(((size_t)b * S_ + s) * H_ + h) * E_ + e];
  }
  __syncthreads();
#pragma unroll
  for (int k2 = 0; k2 < 4; ++k2) {
    int e = et * 32 + ty + 8 * k2;
    int s = st * 32 + tx;
    _Float16 hf = (_Float16)t[tx][ty + 8 * k2];
    vb[(((size_t)b * H_ + h) * E_ + e) * S_ + s] = __builtin_bit_cast(u16, hf);
  }
}

// WG = 8 waves (512 thr) = one 16-row q-tile of one (b,h). 2 WGs/CU.
// P1: all 8 waves: swapped QK^T -> exp -> f16 p in XOR-swizzled LDS (wave = 256 s).
// barrier
// CONCURRENT: waves 0-3 = PV MFMA (e-half x s-half); waves 4-7 = stream a-drain.
// barrier; waves 0-1 combine partner halves and store out.
__global__ __launch_bounds__(512, 4) void attn_fused(
    const u16* __restrict__ qb, const u16* __restrict__ kb,
    const u16* __restrict__ vbuf, const float* __restrict__ dl,
    float* __restrict__ out, float* __restrict__ oa) {
  __shared__ __align__(16) u16 sc[16 * 2048];  // 64 KB swizzled f16 p
  __shared__ float psum[8][16];
  __shared__ float ox[2][16][33];  // partner PV partials (waves 2,3 -> 0,1)

  int bid = blockIdx.x;
  int swz = (bid & 7) * 512 + (bid >> 3);  // 4096 WGs, 8 XCDs
  int b = swz >> 10;
  int h = (swz >> 7) & 7;
  int qt = swz & 127;
  int m0 = qt * 16;
  int tid = threadIdx.x, lane = tid & 63, wave = tid >> 6;  // wave 0..7
  int l15 = lane & 15, l4 = lane >> 4;
  int s0 = wave * 256;
  int xm = (l15 & 7) << 4;  // XOR swizzle (bits 4-6), per-row
  char* scb = (char*)sc;

  // Q fragment (B operand): col q = l15, k(e) = 8*l4 + j
  const u16* qp = qb + (((size_t)b * L_ + (m0 + l15)) * H_ + h) * E_ + 8 * l4;
  bf16x8 qa0 = *(const bf16x8*)qp;
  bf16x8 qa1 = *(const bf16x8*)(qp + 32);

  const u16* kbase = kb + (((size_t)b * S_ + (s0 + l15)) * H_ + h) * E_ + 8 * l4;
  const float* dbase = dl + b * S_ + s0 + 4 * l4;

  // ---- Phase 1: QK^T + exp -> LDS (wave covers 256 s), inline sums ----
  float sums = 0.f;
#pragma unroll 4
  for (int t = 0; t < 16; ++t) {
    const u16* kp = kbase + (size_t)t * (16 * H_ * E_);
    bf16x8 ka0 = *(const bf16x8*)kp;
    bf16x8 ka1 = *(const bf16x8*)(kp + 32);
    f32x4 dv = *(const f32x4*)(dbase + 16 * t);
    f32x4 acc = {0.f, 0.f, 0.f, 0.f};
    acc = __builtin_amdgcn_mfma_f32_16x16x32_bf16(ka0, qa0, acc, 0, 0, 0);
    acc = __builtin_amdgcn_mfma_f32_16x16x32_bf16(ka1, qa1, acc, 0, 0, 0);
    // lane holds D[s = s0+16t+4*l4+r][q = l15]
    float p0 = __builtin_amdgcn_exp2f(acc[0] + dv[0]);
    float p1 = __builtin_amdgcn_exp2f(acc[1] + dv[1]);
    float p2 = __builtin_amdgcn_exp2f(acc[2] + dv[2]);
    float p3 = __builtin_amdgcn_exp2f(acc[3] + dv[3]);
    sums += (p0 + p1) + (p2 + p3);
    f16x4 pv = {(_Float16)p0, (_Float16)p1, (_Float16)p2, (_Float16)p3};
    int off = (l15 << 12) + (((s0 << 1) + (t << 5) + (l4 << 3)) ^ xm);
    *(f16x4*)(scb + off) = pv;
  }
  sums += __shfl_xor(sums, 16, 64);
  sums += __shfl_xor(sums, 32, 64);
  if (lane < 16) psum[wave][lane] = sums;
  __syncthreads();

  f32x4 o0 = {0.f, 0.f, 0.f, 0.f};
  f32x4 o1 = {0.f, 0.f, 0.f, 0.f};
  int eh = wave & 1;  // valid for waves 0-3

  if (wave < 4) {
    // ---- PV: wave = (eh = e-half 32, sh = s-half 1024) ----
    int sh = wave >> 1;
    const u16* vb0 = vbuf + ((size_t)(b * H_ + h) * E_ + 32 * eh + l15) * S_ +
                     sh * 1024 + 8 * l4;
    const char* sch = scb + (l15 << 12) + (sh << 11);
#pragma unroll 4
    for (int c = 0; c < 32; ++c) {
      f16x8 af = *(const f16x8*)(sch + (((c << 6) + (l4 << 4)) ^ xm));
      f16x8 v0 = *(const f16x8*)(vb0 + (c << 5));
      f16x8 v1 = *(const f16x8*)(vb0 + 16 * S_ + (c << 5));
      o0 = __builtin_amdgcn_mfma_f32_16x16x32_f16(af, v0, o0, 0, 0, 0);
      o1 = __builtin_amdgcn_mfma_f32_16x16x32_f16(af, v1, o1, 0, 0, 0);
    }
    if (sh == 1) {
#pragma unroll
      for (int r = 0; r < 4; ++r) {
        ox[eh][4 * l4 + r][l15] = o0[r];
        ox[eh][4 * l4 + r][16 + l15] = o1[r];
      }
    }
  } else {
    // ---- concurrent streaming drain of normalized a (4 rows per wave) ----
    int w4 = wave - 4;
#pragma unroll
    for (int rr = 0; rr < 4; ++rr) {
      int row = w4 * 4 + rr;
      float zrow = psum[0][row] + psum[1][row] + psum[2][row] + psum[3][row] +
                   psum[4][row] + psum[5][row] + psum[6][row] + psum[7][row];
      float zi = 1.f / zrow;
      float* ar = oa + (((size_t)(b * H_ + h)) * L_ + (m0 + row)) * S_;
      int xr = (row & 7) << 4;
      const char* scr = scb + (row << 12);
#pragma unroll
      for (int it = 0; it < 4; ++it) {
        f16x8 pv = *(const f16x8*)(scr + (((it << 10) + (lane << 4)) ^ xr));
        f32x4 lo = {(float)pv[0] * zi, (float)pv[1] * zi,
                    (float)pv[2] * zi, (float)pv[3] * zi};
        f32x4 hi = {(float)pv[4] * zi, (float)pv[5] * zi,
                    (float)pv[6] * zi, (float)pv[7] * zi};
        int col = it * 512 + lane * 8;
        *(f32x4*)(ar + col) = lo;
        *(f32x4*)(ar + col + 4) = hi;
      }
    }
  }
  __syncthreads();

  // ---- out: waves 0,1 (sh==0) combine with partner (sh==1) and store ----
  if (wave < 2) {
#pragma unroll
    for (int r = 0; r < 4; ++r) {
      int row = 4 * l4 + r;
      float zrow = psum[0][row] + psum[1][row] + psum[2][row] + psum[3][row] +
                   psum[4][row] + psum[5][row] + psum[6][row] + psum[7][row];
      float zi = 1.f / zrow;
      size_t ob = (((size_t)b * L_ + (m0 + row)) * H_ + h) * E_ + 32 * eh;
      out[ob + l15] = (o0[r] + ox[eh][row][l15]) * zi;
      out[ob + 16 + l15] = (o1[r] + ox[eh][row][16 + l15]) * zi;
    }
  }
}

extern "C" void kernel_launch(void* const* d_in, const int* in_sizes, int n_in,
                              void* d_out, int out_size, void* d_ws, size_t ws_size,
                              hipStream_t stream) {
  (void)in_sizes; (void)n_in; (void)out_size;
  const float* q = (const float*)d_in[0];
  const float* k = (const float*)d_in[1];
  const float* v = (const float*)d_in[2];
  const float* tau = (const float*)d_in[3];
  const float* delta = (const float*)d_in[4];
  float* out = (float*)d_out;
  float* oa = out + (size_t)B_ * L_ * H_ * E_;

  const size_t NQ = (size_t)B_ * L_ * H_ * E_;  // 4194304
  u16* qb = (u16*)d_ws;
  u16* kb = qb + NQ;
  u16* vb = kb + NQ;
  float* dl = (float*)(vb + NQ);
  size_t need = 3 * NQ * sizeof(u16) + (size_t)B_ * S_ * sizeof(float);
  if (ws_size < need) return;

  prep_qkd<<<4096, 256, 0, stream>>>(q, k, tau, delta, qb, kb, dl);
  prep_v<<<4096, 256, 0, stream>>>(v, vb);
  attn_fused<<<4096, 512, 0, stream>>>(qb, kb, vb, dl, out, oa);
}